// Round 7
// baseline (175.820 us; speedup 1.0000x reference)
//
#include <hip/hip_runtime.h>

#define NN 50000
#define NE 800000
#define NG 256
#define NB 2000       // buckets (by dst)
#define BW 25         // nodes per bucket: NB*BW == NN
#define NBIN 200      // bin blocks
#define EPB 4000      // edges per bin block: NBIN*EPB == NE
#define NGEMM 391     // gemm1 blocks: (NN+127)/128
#define PAD 16        // ints: pad hot atomics to one 64B line
#define CAP 608       // per-bucket region: mean 400, +10.4 sigma
#define WT_STRIDE 136 // LDS W-tile row stride in bf16

typedef __attribute__((ext_vector_type(8))) short bf16x8;
typedef __attribute__((ext_vector_type(4))) float f32x4;
typedef __attribute__((ext_vector_type(2))) float f32x2;

static __device__ __forceinline__ unsigned short f2b(float f) {
    unsigned int u = __float_as_uint(f);
    return (unsigned short)((u + 0x7FFFu + ((u >> 16) & 1u)) >> 16);
}
static __device__ __forceinline__ unsigned char f2e4m3(float f) {
    int p = __builtin_amdgcn_cvt_pk_fp8_f32(f, 0.f, 0, false);
    return (unsigned char)(p & 0xFF);
}

// 1) in-degree histogram (dst only; self-loop handled as +1 in rsqrt)
__global__ __launch_bounds__(256) void k_deg(const int* __restrict__ dst,
                                             int* __restrict__ deg) {
    int i0 = blockIdx.x * 256 + threadIdx.x;
    for (int i = i0; i < NE; i += 256 * 256)
        atomicAdd(&deg[dst[i]], 1);
}

// 2) FUSED front: blocks [0,NGEMM) -> h8 = fp8(dinv_row * (x @ W1)) (deg ready,
//    so scale fused into the MFMA epilogue: single quantization, round-0
//    numerics). Blocks [NGEMM,..) -> bin edges into 2000 dst-buckets.
__global__ __launch_bounds__(256) void k_front(const float* __restrict__ x,
                                               const float* __restrict__ W,
                                               const int* __restrict__ deg,
                                               unsigned char* __restrict__ h8,
                                               const int* __restrict__ src,
                                               const int* __restrict__ dst,
                                               int* __restrict__ bcur,
                                               unsigned int* __restrict__ ebuf) {
    __shared__ __align__(16) unsigned short Ws[128 * WT_STRIDE]; // 34816 B union
    const int tid = threadIdx.x;

    if (blockIdx.x >= NGEMM) {
        // ---- binning path (Ws reused as 3x2000 int scratch = 24 KB) ----
        int* lh = (int*)Ws;
        int* gb = lh + NB;
        int* lc = gb + NB;
        for (int i = tid; i < NB; i += 256) { lh[i] = 0; lc[i] = 0; }
        __syncthreads();
        int e0 = (blockIdx.x - NGEMM) * EPB;
        for (int i = e0 + tid; i < e0 + EPB; i += 256)
            atomicAdd(&lh[(unsigned)dst[i] / BW], 1);
        __syncthreads();
        for (int i = tid; i < NB; i += 256)
            if (lh[i]) gb[i] = i * CAP + atomicAdd(&bcur[i * PAD], lh[i]);
        __syncthreads();
        for (int i = e0 + tid; i < e0 + EPB; i += 256) {  // dst re-read hot
            int d = dst[i];
            int b = (unsigned)d / BW;
            int r = atomicAdd(&lc[b], 1);
            ebuf[gb[b] + r] = ((unsigned)(d - b * BW) << 16) | (unsigned)src[i];
        }
        return;
    }

    // ---- gemm1 path (round-2 staging: compute W->bf16 into LDS) ----
#pragma unroll
    for (int p = 0; p < 64; ++p) {           // 256 thr x 64 = 16384 = 128x128
        int g = p * 256 + tid;
        int k = g >> 7, n = g & 127;         // coalesced read of W[k][n]
        Ws[n * WT_STRIDE + k] = f2b(W[g]);
    }
    __syncthreads();
    const int w = tid >> 6, lane = tid & 63;
    const int q = lane >> 4, lid = lane & 15;
    const int m0 = blockIdx.x * 128 + w * 32;
    f32x4 acc[2][8];
#pragma unroll
    for (int rt = 0; rt < 2; ++rt)
#pragma unroll
        for (int jt = 0; jt < 8; ++jt) acc[rt][jt] = (f32x4){0.f, 0.f, 0.f, 0.f};

#pragma unroll
    for (int kt = 0; kt < 4; ++kt) {
        bf16x8 a[2];
#pragma unroll
        for (int rt = 0; rt < 2; ++rt) {
            int m = m0 + rt * 16 + lid;
            int k0 = kt * 32 + q * 8;
            float4 p0 = make_float4(0.f, 0.f, 0.f, 0.f), p1 = p0;
            if (m < NN) {
                p0 = *(const float4*)(x + (size_t)m * 128 + k0);
                p1 = *(const float4*)(x + (size_t)m * 128 + k0 + 4);
            }
            a[rt][0] = (short)f2b(p0.x); a[rt][1] = (short)f2b(p0.y);
            a[rt][2] = (short)f2b(p0.z); a[rt][3] = (short)f2b(p0.w);
            a[rt][4] = (short)f2b(p1.x); a[rt][5] = (short)f2b(p1.y);
            a[rt][6] = (short)f2b(p1.z); a[rt][7] = (short)f2b(p1.w);
        }
#pragma unroll
        for (int jt = 0; jt < 8; ++jt) {
            bf16x8 b = *(const bf16x8*)(Ws + (jt * 16 + lid) * WT_STRIDE + kt * 32 + q * 8);
            acc[0][jt] = __builtin_amdgcn_mfma_f32_16x16x32_bf16(a[0], b, acc[0][jt], 0, 0, 0);
            acc[1][jt] = __builtin_amdgcn_mfma_f32_16x16x32_bf16(a[1], b, acc[1][jt], 0, 0, 0);
        }
    }
    // epilogue: C/D layout col=lane&15, row=q*4+reg; scale by dinv, store fp8
#pragma unroll
    for (int rt = 0; rt < 2; ++rt)
#pragma unroll
        for (int reg = 0; reg < 4; ++reg) {
            int gr = m0 + rt * 16 + q * 4 + reg;
            if (gr < NN) {
                float di = rsqrtf((float)(deg[gr] + 1));
#pragma unroll
                for (int jt = 0; jt < 8; ++jt)
                    h8[(size_t)gr * 128 + jt * 16 + lid] = f2e4m3(acc[rt][jt][reg] * di);
            }
        }
}

// 3) FUSED sort+aggregate, one block per 25-node bucket (2000 blocks, ~7.8/CU):
//    sort bucket edges in LDS (no csr round-trip), local hist IS the in-degree,
//    aggregate: 1 LDS broadcast + 1 random uint2 load per edge (h8 pre-scaled),
//    fused self-loop + dinv_n scale + bias + relu + sorted-batch max-pool.
__global__ __launch_bounds__(256) void k_sortagg(const unsigned int* __restrict__ ebuf,
                                                 const int* __restrict__ bcur,
                                                 const unsigned char* __restrict__ h8,
                                                 const float* __restrict__ b1,
                                                 const int* __restrict__ batch,
                                                 int* __restrict__ pooled) {
    __shared__ int hist[32], off[32], cur[32];
    __shared__ int stage[CAP];
    __shared__ float vals[16][132];          // +4 pad vs 512B stride
    __shared__ int bts[16];
    const int tid = threadIdx.x;
    const int b = blockIdx.x;
    const int cnt = bcur[b * PAD];
    const int ebeg = b * CAP;
    if (tid < 32) { hist[tid] = 0; cur[tid] = 0; }
    __syncthreads();
    for (int i = tid; i < cnt; i += 256)
        atomicAdd(&hist[ebuf[ebeg + i] >> 16], 1);
    __syncthreads();
    if (tid == 0) {                          // serial 25-elem exclusive scan
        int acc = 0;
#pragma unroll
        for (int l = 0; l < BW; ++l) { off[l] = acc; acc += hist[l]; }
    }
    __syncthreads();
    for (int i = tid; i < cnt; i += 256) {
        unsigned int p = ebuf[ebeg + i];
        int l = p >> 16;
        int r = atomicAdd(&cur[l], 1);
        stage[off[l] + r] = (int)(p & 0xFFFFu);
    }
    __syncthreads();

    const int g = tid >> 4, ql = tid & 15, c = ql * 8;
#pragma unroll
    for (int tile = 0; tile < 2; ++tile) {
        const int l = tile * 16 + g;
        const bool valid = (l < BW);
        const int n = b * BW + l;
        int dg = 0, beg = 0;
        float dd = 0.f;
        if (valid) {
            dg = hist[l];
            beg = off[l];
            dd = rsqrtf((float)(dg + 1));
            if (ql == 0) bts[g] = batch[n];
        }
        float a[8];
#pragma unroll
        for (int j = 0; j < 8; ++j) a[j] = 0.f;
#pragma unroll 4
        for (int i = 0; i < dg; ++i) {
            int s = stage[beg + i];          // LDS broadcast within group
            uint2 v = *(const uint2*)(h8 + (size_t)s * 128 + c);
            f32x2 f0 = __builtin_amdgcn_cvt_pk_f32_fp8((int)v.x, false);
            f32x2 f1 = __builtin_amdgcn_cvt_pk_f32_fp8((int)v.x, true);
            f32x2 f2 = __builtin_amdgcn_cvt_pk_f32_fp8((int)v.y, false);
            f32x2 f3 = __builtin_amdgcn_cvt_pk_f32_fp8((int)v.y, true);
            a[0] += f0.x; a[1] += f0.y; a[2] += f1.x; a[3] += f1.y;
            a[4] += f2.x; a[5] += f2.y; a[6] += f3.x; a[7] += f3.y;
        }
        if (valid) {
            uint2 hv = *(const uint2*)(h8 + (size_t)n * 128 + c);  // self (pre-scaled)
            f32x2 f0 = __builtin_amdgcn_cvt_pk_f32_fp8((int)hv.x, false);
            f32x2 f1 = __builtin_amdgcn_cvt_pk_f32_fp8((int)hv.x, true);
            f32x2 f2 = __builtin_amdgcn_cvt_pk_f32_fp8((int)hv.y, false);
            f32x2 f3 = __builtin_amdgcn_cvt_pk_f32_fp8((int)hv.y, true);
            float4 b0 = *(const float4*)(b1 + c);
            float4 b4 = *(const float4*)(b1 + c + 4);
            float r0 = fmaxf(dd * (a[0] + f0.x) + b0.x, 0.f);
            float r1 = fmaxf(dd * (a[1] + f0.y) + b0.y, 0.f);
            float r2 = fmaxf(dd * (a[2] + f1.x) + b0.z, 0.f);
            float r3 = fmaxf(dd * (a[3] + f1.y) + b0.w, 0.f);
            float r4 = fmaxf(dd * (a[4] + f2.x) + b4.x, 0.f);
            float r5 = fmaxf(dd * (a[5] + f2.y) + b4.y, 0.f);
            float r6 = fmaxf(dd * (a[6] + f3.x) + b4.z, 0.f);
            float r7 = fmaxf(dd * (a[7] + f3.y) + b4.w, 0.f);
            *(float4*)&vals[g][c] = make_float4(r0, r1, r2, r3);
            *(float4*)&vals[g][c + 4] = make_float4(r4, r5, r6, r7);
        }
        __syncthreads();
        if (tid < 128) {
            const int tcnt = (tile == 0) ? 16 : (BW - 16);  // 16 then 9
            float m = vals[0][tid];
            int curb = bts[0];
            for (int ww = 1; ww < tcnt; ++ww) {
                if (bts[ww] != curb) {
                    atomicMax(&pooled[curb * 128 + tid], __float_as_int(m));
                    curb = bts[ww];
                    m = vals[ww][tid];
                } else {
                    m = fmaxf(m, vals[ww][tid]);
                }
            }
            atomicMax(&pooled[curb * 128 + tid], __float_as_int(m));
        }
        __syncthreads();
    }
}

// 4) out = relu(pooled @ W2 + b2)
__global__ __launch_bounds__(256) void k_gemm2(const float* __restrict__ pooled,
                                               const float* __restrict__ W2,
                                               const float* __restrict__ b2,
                                               float* __restrict__ out) {
    const int tid = threadIdx.x;
    const int row = blockIdx.x * 4 + (tid >> 6);
    const int col = tid & 63;
    const float* p = pooled + row * 128;
    float acc = b2[col];
    for (int k = 0; k < 128; ++k) acc += p[k] * W2[k * 64 + col];
    out[row * 64 + col] = fmaxf(acc, 0.f);
}

extern "C" void kernel_launch(void* const* d_in, const int* in_sizes, int n_in,
                              void* d_out, int out_size, void* d_ws, size_t ws_size,
                              hipStream_t stream) {
    const float* x     = (const float*)d_in[0];
    const int*   ei    = (const int*)d_in[1];   // [2, NE]: src row then dst row
    const int*   batch = (const int*)d_in[2];
    const float* W1    = (const float*)d_in[3];
    const float* b1    = (const float*)d_in[4];
    const float* W2    = (const float*)d_in[5];
    const float* b2    = (const float*)d_in[6];
    float* out = (float*)d_out;

    // ws layout (int units):
    // [zeroed: pooled NG*128 | bcur NB*PAD | deg NN] ebuf NB*CAP | h8 NN*128 B
    int*   pooled  = (int*)d_ws;
    int*   bcur    = pooled + (size_t)NG * 128;
    int*   deg     = bcur + (size_t)NB * PAD;
    unsigned int* ebuf = (unsigned int*)(deg + NN);
    unsigned char* h8  = (unsigned char*)(ebuf + (size_t)NB * CAP);

    size_t zbytes = ((size_t)NG * 128 + (size_t)NB * PAD + NN) * 4;
    hipMemsetAsync(d_ws, 0, zbytes, stream);

    const int* srcv = ei;
    const int* dstv = ei + NE;

    k_deg<<<256, 256, 0, stream>>>(dstv, deg);
    k_front<<<NGEMM + NBIN, 256, 0, stream>>>(x, W1, deg, h8, srcv, dstv, bcur, ebuf);
    k_sortagg<<<NB, 256, 0, stream>>>(ebuf, bcur, h8, b1, batch, pooled);
    k_gemm2<<<NG / 4, 256, 0, stream>>>((const float*)pooled, W2, b2, out);
}

// Round 8
// 172.416 us; speedup vs baseline: 1.0197x; 1.0197x over previous
//
#include <hip/hip_runtime.h>

#define NN 50000
#define NE 800000
#define NG 256
#define NB 256        // buckets
#define BW 196        // nodes per bucket
#define NBIN 200      // k_bin blocks
#define EPB 4000      // edges per bin block: NBIN*EPB == NE
#define NGEMM 391     // gemm1 blocks: (NN+127)/128
#define PAD 16        // ints: pad hot atomics to one 64B line
#define CAP 4352      // fixed region per bucket (mean 3136, +21.7 sigma)
#define WT_STRIDE 136 // LDS W-tile row stride in bf16

typedef __attribute__((ext_vector_type(8))) short bf16x8;
typedef __attribute__((ext_vector_type(4))) float f32x4;
typedef __attribute__((ext_vector_type(2))) float f32x2;

static __device__ __forceinline__ unsigned short f2b(float f) {
    unsigned int u = __float_as_uint(f);
    return (unsigned short)((u + 0x7FFFu + ((u >> 16) & 1u)) >> 16);
}
static __device__ __forceinline__ unsigned char f2e4m3(float f) {
    int p = __builtin_amdgcn_cvt_pk_fp8_f32(f, 0.f, 0, false);
    return (unsigned char)(p & 0xFF);
}

// 0) in-degree histogram (dst only; self-loop is the +1 in rsqrt).
//    Runs BEFORE k_front so gemm1 can fold dinv into its epilogue.
__global__ __launch_bounds__(256) void k_deg(const int* __restrict__ dst,
                                             int* __restrict__ degp) {
    int i0 = blockIdx.x * 256 + threadIdx.x;
    for (int i = i0; i < NE; i += 256 * 256)
        atomicAdd(&degp[dst[i]], 1);
}

// 1) FUSED front kernel: blocks [0, NGEMM) do h8 = fp8(dinv_row * (x @ W1))
//    (single quantization, round-0 numerics); blocks [NGEMM, ...) bin edges
//    into per-bucket regions of ebuf (packed ldst<<17|src).
__global__ __launch_bounds__(256) void k_front(const float* __restrict__ x,
                                               const float* __restrict__ W,
                                               const int* __restrict__ degp,
                                               unsigned char* __restrict__ h8,
                                               const int* __restrict__ src,
                                               const int* __restrict__ dst,
                                               int* __restrict__ bcur,
                                               unsigned int* __restrict__ ebuf) {
    __shared__ unsigned short Ws[128 * WT_STRIDE];   // 34816 B, both paths
    const int tid = threadIdx.x;

    if (blockIdx.x >= NGEMM) {
        // ---- binning path (first 3 KB of Ws as int scratch) ----
        int* lh = (int*)Ws;
        int* gb = lh + NB;
        int* lc = gb + NB;
        lh[tid] = 0; lc[tid] = 0;
        __syncthreads();
        int e0 = (blockIdx.x - NGEMM) * EPB;
        for (int i = e0 + tid; i < e0 + EPB; i += 256)
            atomicAdd(&lh[(unsigned)dst[i] / BW], 1);
        __syncthreads();
        if (lh[tid]) gb[tid] = tid * CAP + atomicAdd(&bcur[tid * PAD], lh[tid]);
        __syncthreads();
        for (int i = e0 + tid; i < e0 + EPB; i += 256) {  // dst re-read hot
            int d = dst[i];
            int b = (unsigned)d / BW;
            int r = atomicAdd(&lc[b], 1);
            ebuf[gb[b] + r] = ((unsigned)(d - b * BW) << 17) | (unsigned)src[i];
        }
        return;
    }

    // ---- gemm1 path: h8(fp8 e4m3) = dinv * (x @ W1), MFMA 16x16x32 bf16 ----
#pragma unroll
    for (int p = 0; p < 64; ++p) {           // 256 thr x 64 = 16384 = 128x128
        int g = p * 256 + tid;
        int k = g >> 7, n = g & 127;         // coalesced read of W[k][n]
        Ws[n * WT_STRIDE + k] = f2b(W[g]);
    }
    __syncthreads();
    const int w = tid >> 6, lane = tid & 63;
    const int q = lane >> 4, lid = lane & 15;
    const int m0 = blockIdx.x * 128 + w * 32;
    f32x4 acc[2][8];
#pragma unroll
    for (int rt = 0; rt < 2; ++rt)
#pragma unroll
        for (int jt = 0; jt < 8; ++jt) acc[rt][jt] = (f32x4){0.f, 0.f, 0.f, 0.f};

#pragma unroll
    for (int kt = 0; kt < 4; ++kt) {
        bf16x8 a[2];
#pragma unroll
        for (int rt = 0; rt < 2; ++rt) {
            int m = m0 + rt * 16 + lid;
            int k0 = kt * 32 + q * 8;
            float4 p0 = make_float4(0.f, 0.f, 0.f, 0.f), p1 = p0;
            if (m < NN) {
                p0 = *(const float4*)(x + (size_t)m * 128 + k0);
                p1 = *(const float4*)(x + (size_t)m * 128 + k0 + 4);
            }
            a[rt][0] = (short)f2b(p0.x); a[rt][1] = (short)f2b(p0.y);
            a[rt][2] = (short)f2b(p0.z); a[rt][3] = (short)f2b(p0.w);
            a[rt][4] = (short)f2b(p1.x); a[rt][5] = (short)f2b(p1.y);
            a[rt][6] = (short)f2b(p1.z); a[rt][7] = (short)f2b(p1.w);
        }
#pragma unroll
        for (int jt = 0; jt < 8; ++jt) {
            bf16x8 b = *(const bf16x8*)(Ws + (jt * 16 + lid) * WT_STRIDE + kt * 32 + q * 8);
            acc[0][jt] = __builtin_amdgcn_mfma_f32_16x16x32_bf16(a[0], b, acc[0][jt], 0, 0, 0);
            acc[1][jt] = __builtin_amdgcn_mfma_f32_16x16x32_bf16(a[1], b, acc[1][jt], 0, 0, 0);
        }
    }
    // epilogue: C/D layout col=lane&15, row=q*4+reg; scale by dinv, store fp8
#pragma unroll
    for (int rt = 0; rt < 2; ++rt)
#pragma unroll
        for (int reg = 0; reg < 4; ++reg) {
            int gr = m0 + rt * 16 + q * 4 + reg;
            if (gr < NN) {
                float di = rsqrtf((float)(degp[gr] + 1));
#pragma unroll
                for (int jt = 0; jt < 8; ++jt)
                    h8[(size_t)gr * 128 + jt * 16 + lid] = f2e4m3(acc[rt][jt][reg] * di);
            }
        }
}

// 2) per-bucket counting sort into bucket-local csr region [b*CAP, ...).
//    rowptr global index into csr_src; deg/dinv fused. No cross-bucket scan.
__global__ __launch_bounds__(256) void k_sort(const unsigned int* __restrict__ ebuf,
                                              const int* __restrict__ bcur,
                                              int* __restrict__ csr_src,
                                              int* __restrict__ rowptr,
                                              int* __restrict__ deg,
                                              float* __restrict__ dinv) {
    __shared__ int hist[NB], off[NB], cur[NB];
    __shared__ int stage[CAP];
    const int t = threadIdx.x;
    const int b = blockIdx.x;
    const int cnt = bcur[b * PAD];
    const int ebeg = b * CAP;
    const int nbase = b * BW;
    hist[t] = 0; cur[t] = 0;
    __syncthreads();
    for (int i = t; i < cnt; i += 256)
        atomicAdd(&hist[ebuf[ebeg + i] >> 17], 1);
    __syncthreads();
    int v = hist[t];
    off[t] = v;
    __syncthreads();
    for (int o = 1; o < NB; o <<= 1) {
        int u = (t >= o) ? off[t - o] : 0;
        __syncthreads();
        off[t] += u;
        __syncthreads();
    }
    int ex = off[t] - v;
    int gn = nbase + t;
    if (t < BW && gn < NN) {
        rowptr[gn] = ebeg + ex;
        deg[gn] = v;
        dinv[gn] = rsqrtf((float)(v + 1));
    }
    __syncthreads();
    off[t] = ex;
    __syncthreads();
    for (int i = t; i < cnt; i += 256) {
        unsigned int p = ebuf[ebeg + i];
        int l = p >> 17;
        int r = atomicAdd(&cur[l], 1);
        stage[off[l] + r] = (int)(p & 0x1FFFFu);
    }
    __syncthreads();
    for (int i = t; i < cnt; i += 256)
        csr_src[ebeg + i] = stage[i];
}

// 3) aggregation: quarter-wave (16 lanes x 8ch fp8 uint2) owns ONE dst node.
//    h8 is PRE-SCALED by dinv[src] (round-0 numerics) -> inner loop is
//    2 VMEM/edge (csr broadcast + h8 row). Fused bias+relu+sorted max-pool.
__global__ __launch_bounds__(256) void k_agg(const unsigned char* __restrict__ h8,
                                             const int* __restrict__ csr_src,
                                             const int* __restrict__ rowptr,
                                             const int* __restrict__ deg,
                                             const float* __restrict__ dinv,
                                             const float* __restrict__ b1,
                                             const int* __restrict__ batch,
                                             int* __restrict__ pooled) {
    const int tid = threadIdx.x;
    const int qg = tid >> 4, ql = tid & 15;
    const int n = blockIdx.x * 16 + qg;      // NN = 3125*16, no tail
    __shared__ float vals[16][128];
    __shared__ int bts[16];
    if (ql == 0) bts[qg] = batch[n];
    const float dd = dinv[n];
    const int beg = rowptr[n];
    const int end = beg + deg[n];
    const int c = ql * 8;
    float a[8];
#pragma unroll
    for (int j = 0; j < 8; ++j) a[j] = 0.f;
#pragma unroll 4
    for (int i = beg; i < end; ++i) {
        int s = csr_src[i];
        uint2 v = *(const uint2*)(h8 + (size_t)s * 128 + c);
        f32x2 f0 = __builtin_amdgcn_cvt_pk_f32_fp8((int)v.x, false);
        f32x2 f1 = __builtin_amdgcn_cvt_pk_f32_fp8((int)v.x, true);
        f32x2 f2 = __builtin_amdgcn_cvt_pk_f32_fp8((int)v.y, false);
        f32x2 f3 = __builtin_amdgcn_cvt_pk_f32_fp8((int)v.y, true);
        a[0] += f0.x; a[1] += f0.y; a[2] += f1.x; a[3] += f1.y;
        a[4] += f2.x; a[5] += f2.y; a[6] += f3.x; a[7] += f3.y;
    }
    {
        uint2 hv = *(const uint2*)(h8 + (size_t)n * 128 + c);  // self, pre-scaled
        f32x2 f0 = __builtin_amdgcn_cvt_pk_f32_fp8((int)hv.x, false);
        f32x2 f1 = __builtin_amdgcn_cvt_pk_f32_fp8((int)hv.x, true);
        f32x2 f2 = __builtin_amdgcn_cvt_pk_f32_fp8((int)hv.y, false);
        f32x2 f3 = __builtin_amdgcn_cvt_pk_f32_fp8((int)hv.y, true);
        float4 b0 = *(const float4*)(b1 + c);
        float4 b4 = *(const float4*)(b1 + c + 4);
        float r0 = fmaxf(dd * (a[0] + f0.x) + b0.x, 0.f);
        float r1 = fmaxf(dd * (a[1] + f0.y) + b0.y, 0.f);
        float r2 = fmaxf(dd * (a[2] + f1.x) + b0.z, 0.f);
        float r3 = fmaxf(dd * (a[3] + f1.y) + b0.w, 0.f);
        float r4 = fmaxf(dd * (a[4] + f2.x) + b4.x, 0.f);
        float r5 = fmaxf(dd * (a[5] + f2.y) + b4.y, 0.f);
        float r6 = fmaxf(dd * (a[6] + f3.x) + b4.z, 0.f);
        float r7 = fmaxf(dd * (a[7] + f3.y) + b4.w, 0.f);
        *(float4*)&vals[qg][c] = make_float4(r0, r1, r2, r3);
        *(float4*)&vals[qg][c + 4] = make_float4(r4, r5, r6, r7);
    }
    __syncthreads();
    if (tid < 128) {
        float m = vals[0][tid];
        int cur = bts[0];
#pragma unroll
        for (int ww = 1; ww < 16; ++ww) {
            if (bts[ww] != cur) {
                atomicMax(&pooled[cur * 128 + tid], __float_as_int(m));
                cur = bts[ww];
                m = vals[ww][tid];
            } else {
                m = fmaxf(m, vals[ww][tid]);
            }
        }
        atomicMax(&pooled[cur * 128 + tid], __float_as_int(m));
    }
}

// 4) out = relu(pooled @ W2 + b2)
__global__ __launch_bounds__(256) void k_gemm2(const float* __restrict__ pooled,
                                               const float* __restrict__ W2,
                                               const float* __restrict__ b2,
                                               float* __restrict__ out) {
    const int tid = threadIdx.x;
    const int row = blockIdx.x * 4 + (tid >> 6);
    const int col = tid & 63;
    const float* p = pooled + row * 128;
    float acc = b2[col];
    for (int k = 0; k < 128; ++k) acc += p[k] * W2[k * 64 + col];
    out[row * 64 + col] = fmaxf(acc, 0.f);
}

extern "C" void kernel_launch(void* const* d_in, const int* in_sizes, int n_in,
                              void* d_out, int out_size, void* d_ws, size_t ws_size,
                              hipStream_t stream) {
    const float* x     = (const float*)d_in[0];
    const int*   ei    = (const int*)d_in[1];   // [2, NE]: src row then dst row
    const int*   batch = (const int*)d_in[2];
    const float* W1    = (const float*)d_in[3];
    const float* b1    = (const float*)d_in[4];
    const float* W2    = (const float*)d_in[5];
    const float* b2    = (const float*)d_in[6];
    float* out = (float*)d_out;

    // ws layout (int units), footprint < round-2 (CAP 4608->4352 pays for degp):
    // [zeroed: pooled NG*128 | bcur NB*PAD | degp NN] rowptr NN | deg NN |
    // dinv NN | csr_src NB*CAP | ebuf NB*CAP | h8 NN*128 bytes
    int*   pooled  = (int*)d_ws;
    int*   bcur    = pooled + (size_t)NG * 128;
    int*   degp    = bcur + NB * PAD;
    int*   rowptr  = degp + NN;
    int*   deg     = rowptr + NN;
    float* dinv    = (float*)(deg + NN);
    int*   csr_src = (int*)(dinv + NN);
    unsigned int* ebuf = (unsigned int*)(csr_src + (size_t)NB * CAP);
    unsigned char* h8  = (unsigned char*)(ebuf + (size_t)NB * CAP);

    size_t zbytes = ((size_t)NG * 128 + NB * PAD + NN) * 4;
    hipMemsetAsync(d_ws, 0, zbytes, stream);

    const int* srcv = ei;
    const int* dstv = ei + NE;

    k_deg<<<256, 256, 0, stream>>>(dstv, degp);
    k_front<<<NGEMM + NBIN, 256, 0, stream>>>(x, W1, degp, h8, srcv, dstv, bcur, ebuf);
    k_sort<<<NB, 256, 0, stream>>>(ebuf, bcur, csr_src, rowptr, deg, dinv);
    k_agg<<<NN / 16, 256, 0, stream>>>(h8, csr_src, rowptr, deg, dinv, b1, batch, pooled);
    k_gemm2<<<NG / 4, 256, 0, stream>>>((const float*)pooled, W2, b2, out);
}

// Round 9
// 137.384 us; speedup vs baseline: 1.2798x; 1.2550x over previous
//
#include <hip/hip_runtime.h>

#define NN 50000
#define NE 800000
#define NG 256
#define NB 256        // buckets
#define BW 196        // nodes per bucket
#define NBIN 200      // k_bin blocks
#define EPB 4000      // edges per bin block: NBIN*EPB == NE
#define NGEMM 391     // gemm1 blocks: (NN+127)/128
#define PAD 16        // ints: pad hot atomics to one 64B line
#define CAP 4608      // fixed region per bucket (mean 3136, +26 sigma)
#define WT_STRIDE 136 // LDS W-tile row stride in bf16

typedef __attribute__((ext_vector_type(8))) short bf16x8;
typedef __attribute__((ext_vector_type(4))) float f32x4;
typedef __attribute__((ext_vector_type(2))) float f32x2;

static __device__ __forceinline__ unsigned short f2b(float f) {
    unsigned int u = __float_as_uint(f);
    return (unsigned short)((u + 0x7FFFu + ((u >> 16) & 1u)) >> 16);
}

// 1) FUSED front kernel: blocks [0, NGEMM) do h8 = fp8(x @ W1) (no dinv —
//    deferred to k_agg); blocks [NGEMM, ...) bin edges into ebuf regions.
//    h8 byte layout is PERMUTED: byte (lid*8 + jt) of row gr holds the value
//    of output col (jt*16 + lid). This makes each thread's 8 epilogue bytes
//    contiguous -> ONE dwordx2 store per row-slice instead of 64 byte-stores.
__global__ __launch_bounds__(256) void k_front(const float* __restrict__ x,
                                               const float* __restrict__ W,
                                               unsigned char* __restrict__ h8,
                                               const int* __restrict__ src,
                                               const int* __restrict__ dst,
                                               int* __restrict__ bcur,
                                               unsigned int* __restrict__ ebuf) {
    __shared__ unsigned short Ws[128 * WT_STRIDE];   // 34816 B, both paths
    const int tid = threadIdx.x;

    if (blockIdx.x >= NGEMM) {
        // ---- binning path (first 3 KB of Ws as int scratch) ----
        int* lh = (int*)Ws;
        int* gb = lh + NB;
        int* lc = gb + NB;
        lh[tid] = 0; lc[tid] = 0;
        __syncthreads();
        int e0 = (blockIdx.x - NGEMM) * EPB;
        for (int i = e0 + tid; i < e0 + EPB; i += 256)
            atomicAdd(&lh[(unsigned)dst[i] / BW], 1);
        __syncthreads();
        if (lh[tid]) gb[tid] = tid * CAP + atomicAdd(&bcur[tid * PAD], lh[tid]);
        __syncthreads();
        for (int i = e0 + tid; i < e0 + EPB; i += 256) {  // dst re-read hot
            int d = dst[i];
            int b = (unsigned)d / BW;
            int r = atomicAdd(&lc[b], 1);
            ebuf[gb[b] + r] = ((unsigned)(d - b * BW) << 17) | (unsigned)src[i];
        }
        return;
    }

    // ---- gemm1 path: h8(fp8 e4m3) = x @ W1 (unscaled), MFMA 16x16x32 bf16 ----
#pragma unroll
    for (int p = 0; p < 64; ++p) {           // 256 thr x 64 = 16384 = 128x128
        int g = p * 256 + tid;
        int k = g >> 7, n = g & 127;         // coalesced read of W[k][n]
        Ws[n * WT_STRIDE + k] = f2b(W[g]);
    }
    __syncthreads();
    const int w = tid >> 6, lane = tid & 63;
    const int q = lane >> 4, lid = lane & 15;
    const int m0 = blockIdx.x * 128 + w * 32;
    f32x4 acc[2][8];
#pragma unroll
    for (int rt = 0; rt < 2; ++rt)
#pragma unroll
        for (int jt = 0; jt < 8; ++jt) acc[rt][jt] = (f32x4){0.f, 0.f, 0.f, 0.f};

#pragma unroll
    for (int kt = 0; kt < 4; ++kt) {
        bf16x8 a[2];
#pragma unroll
        for (int rt = 0; rt < 2; ++rt) {
            int m = m0 + rt * 16 + lid;
            int k0 = kt * 32 + q * 8;
            float4 p0 = make_float4(0.f, 0.f, 0.f, 0.f), p1 = p0;
            if (m < NN) {
                p0 = *(const float4*)(x + (size_t)m * 128 + k0);
                p1 = *(const float4*)(x + (size_t)m * 128 + k0 + 4);
            }
            a[rt][0] = (short)f2b(p0.x); a[rt][1] = (short)f2b(p0.y);
            a[rt][2] = (short)f2b(p0.z); a[rt][3] = (short)f2b(p0.w);
            a[rt][4] = (short)f2b(p1.x); a[rt][5] = (short)f2b(p1.y);
            a[rt][6] = (short)f2b(p1.z); a[rt][7] = (short)f2b(p1.w);
        }
#pragma unroll
        for (int jt = 0; jt < 8; ++jt) {
            bf16x8 b = *(const bf16x8*)(Ws + (jt * 16 + lid) * WT_STRIDE + kt * 32 + q * 8);
            acc[0][jt] = __builtin_amdgcn_mfma_f32_16x16x32_bf16(a[0], b, acc[0][jt], 0, 0, 0);
            acc[1][jt] = __builtin_amdgcn_mfma_f32_16x16x32_bf16(a[1], b, acc[1][jt], 0, 0, 0);
        }
    }
    // epilogue: C/D layout col=lane&15, row=q*4+reg. Pack the 8 jt-values of
    // one row into 2 dwords (4x cvt_pk) and store ONE uint2 at byte lid*8.
#pragma unroll
    for (int rt = 0; rt < 2; ++rt)
#pragma unroll
        for (int reg = 0; reg < 4; ++reg) {
            int gr = m0 + rt * 16 + q * 4 + reg;
            if (gr < NN) {
                int d0 = __builtin_amdgcn_cvt_pk_fp8_f32(acc[rt][0][reg], acc[rt][1][reg], 0, false);
                d0 = __builtin_amdgcn_cvt_pk_fp8_f32(acc[rt][2][reg], acc[rt][3][reg], d0, true);
                int d1 = __builtin_amdgcn_cvt_pk_fp8_f32(acc[rt][4][reg], acc[rt][5][reg], 0, false);
                d1 = __builtin_amdgcn_cvt_pk_fp8_f32(acc[rt][6][reg], acc[rt][7][reg], d1, true);
                *(uint2*)(h8 + (size_t)gr * 128 + lid * 8) = make_uint2((unsigned)d0, (unsigned)d1);
            }
        }
}

// 2) per-bucket counting sort into bucket-local csr region [b*CAP, ...).
//    rowptr global index into csr_src; deg/dinv fused. No cross-bucket scan.
__global__ __launch_bounds__(256) void k_sort(const unsigned int* __restrict__ ebuf,
                                              const int* __restrict__ bcur,
                                              int* __restrict__ csr_src,
                                              int* __restrict__ rowptr,
                                              int* __restrict__ deg,
                                              float* __restrict__ dinv) {
    __shared__ int hist[NB], off[NB], cur[NB];
    __shared__ int stage[CAP];
    const int t = threadIdx.x;
    const int b = blockIdx.x;
    const int cnt = bcur[b * PAD];
    const int ebeg = b * CAP;
    const int nbase = b * BW;
    hist[t] = 0; cur[t] = 0;
    __syncthreads();
    for (int i = t; i < cnt; i += 256)
        atomicAdd(&hist[ebuf[ebeg + i] >> 17], 1);
    __syncthreads();
    int v = hist[t];
    off[t] = v;
    __syncthreads();
    for (int o = 1; o < NB; o <<= 1) {
        int u = (t >= o) ? off[t - o] : 0;
        __syncthreads();
        off[t] += u;
        __syncthreads();
    }
    int ex = off[t] - v;
    int gn = nbase + t;
    if (t < BW && gn < NN) {
        rowptr[gn] = ebeg + ex;
        deg[gn] = v;
        dinv[gn] = rsqrtf((float)(v + 1));
    }
    __syncthreads();
    off[t] = ex;
    __syncthreads();
    for (int i = t; i < cnt; i += 256) {
        unsigned int p = ebuf[ebeg + i];
        int l = p >> 17;
        int r = atomicAdd(&cur[l], 1);
        stage[off[l] + r] = (int)(p & 0x1FFFFu);
    }
    __syncthreads();
    for (int i = t; i < cnt; i += 256)
        csr_src[ebeg + i] = stage[i];
}

// 3) aggregation: quarter-wave (16 lanes x 8ch fp8 uint2) owns ONE dst node.
//    h8 permuted layout: thread ql's decoded a[j] is actual col (j*16 + ql).
//    Bias gathered as b1[j*16+ql]; pooled write un-permutes the channel index
//    so k_gemm2 is unchanged. Per-edge dinv[s] (h8 unscaled), fused
//    bias+relu+sorted-batch max-pool.
__global__ __launch_bounds__(256) void k_agg(const unsigned char* __restrict__ h8,
                                             const int* __restrict__ csr_src,
                                             const int* __restrict__ rowptr,
                                             const int* __restrict__ deg,
                                             const float* __restrict__ dinv,
                                             const float* __restrict__ b1,
                                             const int* __restrict__ batch,
                                             int* __restrict__ pooled) {
    const int tid = threadIdx.x;
    const int qg = tid >> 4, ql = tid & 15;
    const int n = blockIdx.x * 16 + qg;      // NN = 3125*16, no tail
    __shared__ float vals[16][128];
    __shared__ int bts[16];
    if (ql == 0) bts[qg] = batch[n];
    const float dd = dinv[n];
    const int beg = rowptr[n];
    const int end = beg + deg[n];
    const int c = ql * 8;
    float a[8];
#pragma unroll
    for (int j = 0; j < 8; ++j) a[j] = 0.f;
#pragma unroll 4
    for (int i = beg; i < end; ++i) {
        int s = csr_src[i];
        float ds = dinv[s];
        uint2 v = *(const uint2*)(h8 + (size_t)s * 128 + c);
        f32x2 f0 = __builtin_amdgcn_cvt_pk_f32_fp8((int)v.x, false);
        f32x2 f1 = __builtin_amdgcn_cvt_pk_f32_fp8((int)v.x, true);
        f32x2 f2 = __builtin_amdgcn_cvt_pk_f32_fp8((int)v.y, false);
        f32x2 f3 = __builtin_amdgcn_cvt_pk_f32_fp8((int)v.y, true);
        a[0] = fmaf(ds, f0.x, a[0]); a[1] = fmaf(ds, f0.y, a[1]);
        a[2] = fmaf(ds, f1.x, a[2]); a[3] = fmaf(ds, f1.y, a[3]);
        a[4] = fmaf(ds, f2.x, a[4]); a[5] = fmaf(ds, f2.y, a[5]);
        a[6] = fmaf(ds, f3.x, a[6]); a[7] = fmaf(ds, f3.y, a[7]);
    }
    {
        // self loop: + dinv[n]*h[n], whole sum scaled by dinv[n]
        uint2 hv = *(const uint2*)(h8 + (size_t)n * 128 + c);
        f32x2 f0 = __builtin_amdgcn_cvt_pk_f32_fp8((int)hv.x, false);
        f32x2 f1 = __builtin_amdgcn_cvt_pk_f32_fp8((int)hv.x, true);
        f32x2 f2 = __builtin_amdgcn_cvt_pk_f32_fp8((int)hv.y, false);
        f32x2 f3 = __builtin_amdgcn_cvt_pk_f32_fp8((int)hv.y, true);
        // permuted bias: decoded value j belongs to actual col j*16 + ql
        float bb[8];
#pragma unroll
        for (int j = 0; j < 8; ++j) bb[j] = b1[j * 16 + ql];
        float r0 = fmaxf(dd * fmaf(dd, f0.x, a[0]) + bb[0], 0.f);
        float r1 = fmaxf(dd * fmaf(dd, f0.y, a[1]) + bb[1], 0.f);
        float r2 = fmaxf(dd * fmaf(dd, f1.x, a[2]) + bb[2], 0.f);
        float r3 = fmaxf(dd * fmaf(dd, f1.y, a[3]) + bb[3], 0.f);
        float r4 = fmaxf(dd * fmaf(dd, f2.x, a[4]) + bb[4], 0.f);
        float r5 = fmaxf(dd * fmaf(dd, f2.y, a[5]) + bb[5], 0.f);
        float r6 = fmaxf(dd * fmaf(dd, f3.x, a[6]) + bb[6], 0.f);
        float r7 = fmaxf(dd * fmaf(dd, f3.y, a[7]) + bb[7], 0.f);
        *(float4*)&vals[qg][c] = make_float4(r0, r1, r2, r3);
        *(float4*)&vals[qg][c + 4] = make_float4(r4, r5, r6, r7);
    }
    __syncthreads();
    if (tid < 128) {
        // vals is in permuted channel space (stored idx tid); un-permute on
        // the pooled write so gemm2 sees actual channel order.
        const int pcol = ((tid & 7) << 4) | (tid >> 3);
        float m = vals[0][tid];
        int cur = bts[0];
#pragma unroll
        for (int ww = 1; ww < 16; ++ww) {
            if (bts[ww] != cur) {
                atomicMax(&pooled[cur * 128 + pcol], __float_as_int(m));
                cur = bts[ww];
                m = vals[ww][tid];
            } else {
                m = fmaxf(m, vals[ww][tid]);
            }
        }
        atomicMax(&pooled[cur * 128 + pcol], __float_as_int(m));
    }
}

// 4) out = relu(pooled @ W2 + b2)
__global__ __launch_bounds__(256) void k_gemm2(const float* __restrict__ pooled,
                                               const float* __restrict__ W2,
                                               const float* __restrict__ b2,
                                               float* __restrict__ out) {
    const int tid = threadIdx.x;
    const int row = blockIdx.x * 4 + (tid >> 6);
    const int col = tid & 63;
    const float* p = pooled + row * 128;
    float acc = b2[col];
    for (int k = 0; k < 128; ++k) acc += p[k] * W2[k * 64 + col];
    out[row * 64 + col] = fmaxf(acc, 0.f);
}

extern "C" void kernel_launch(void* const* d_in, const int* in_sizes, int n_in,
                              void* d_out, int out_size, void* d_ws, size_t ws_size,
                              hipStream_t stream) {
    const float* x     = (const float*)d_in[0];
    const int*   ei    = (const int*)d_in[1];   // [2, NE]: src row then dst row
    const int*   batch = (const int*)d_in[2];
    const float* W1    = (const float*)d_in[3];
    const float* b1    = (const float*)d_in[4];
    const float* W2    = (const float*)d_in[5];
    const float* b2    = (const float*)d_in[6];
    float* out = (float*)d_out;

    // ws layout (int units) — IDENTICAL to the round-2 passing run:
    // [zeroed: pooled NG*128 | bcur NB*PAD] rowptr NN | deg NN | dinv NN |
    // csr_src NB*CAP | ebuf NB*CAP | h8 NN*128 bytes
    int*   pooled  = (int*)d_ws;
    int*   bcur    = pooled + (size_t)NG * 128;
    int*   rowptr  = bcur + NB * PAD;
    int*   deg     = rowptr + NN;
    float* dinv    = (float*)(deg + NN);
    int*   csr_src = (int*)(dinv + NN);
    unsigned int* ebuf = (unsigned int*)(csr_src + (size_t)NB * CAP);
    unsigned char* h8  = (unsigned char*)(ebuf + (size_t)NB * CAP);

    size_t zbytes = ((size_t)NG * 128 + NB * PAD) * 4;
    hipMemsetAsync(d_ws, 0, zbytes, stream);

    const int* srcv = ei;
    const int* dstv = ei + NE;

    k_front<<<NGEMM + NBIN, 256, 0, stream>>>(x, W1, h8, srcv, dstv, bcur, ebuf);
    k_sort<<<NB, 256, 0, stream>>>(ebuf, bcur, csr_src, rowptr, deg, dinv);
    k_agg<<<NN / 16, 256, 0, stream>>>(h8, csr_src, rowptr, deg, dinv, b1, batch, pooled);
    k_gemm2<<<NG / 4, 256, 0, stream>>>((const float*)pooled, W2, b2, out);
}